// Round 8
// baseline (292.698 us; speedup 1.0000x reference)
//
#include <hip/hip_runtime.h>

// DeepSets fused kernel for MI355X (gfx950) — round 7 design (resubmit; r7
// bench died with UnresponsiveContainer before the job was delivered).
// r6 failed: 4-col split needed ~160 weight VGPRs -> spill (VGPR=128 + scratch).
// r7: revert to r5's proven 2-col split (80 weight VGPRs), but restructure for
// OCCUPANCY: rt-outer loops keep only 8 acc regs live -> total ~120 regs ->
// 4 waves/SIMD tier (waves_per_eu(4,4)); single-buffer h1s -> 50KB LDS ->
// 2 blocks/CU. LDS/MFMA/VALU phases now overlap across 16 waves/CU.
// Keep r6's split-K tail + L3 pre-warm (saved ~10us).

typedef unsigned short u16;
typedef _Float16 f16x8 __attribute__((ext_vector_type(8)));
typedef _Float16 f16x4 __attribute__((ext_vector_type(4)));
typedef float f32x4 __attribute__((ext_vector_type(4)));
typedef int i32x4 __attribute__((ext_vector_type(4)));

#define NBLK 512   // 2 blocks/CU

// ---------------- prep: fp32 weights -> fp16 fragments, zero gsum, warm L3 ---
// Fragment layout (validated r1-r6): lane l, elem j holds W[k=32*ks+8*(l>>4)+j][16*ctg+(l&15)]
// at frag[((ctg*KS+ks)*64 + l)*8 + j]. Used as MFMA *A* operand: D = W^T X^T = (XW)^T.
__global__ void prep_kernel(const float* __restrict__ pw1, const float* __restrict__ pw2,
                            _Float16* __restrict__ w1f, _Float16* __restrict__ w2f,
                            float* __restrict__ gsum,
                            const float* __restrict__ pw3, const float* __restrict__ rw1,
                            const float* __restrict__ rw2, const float* __restrict__ rw3,
                            const float* __restrict__ hw1, const float* __restrict__ hw2,
                            const float* __restrict__ hw3) {
    int idx = blockIdx.x * blockDim.x + threadIdx.x;   // 160*512 = 81920
    if (idx < 256) gsum[idx] = 0.f;
    if (idx < 16384) {  // pw1: 64x256, KS=2
        int j = idx & 7, l = (idx >> 3) & 63, ks = (idx >> 9) & 1, ct = idx >> 10;
        int k = 32 * ks + 8 * (l >> 4) + j;
        int col = 16 * ct + (l & 15);
        w1f[idx] = (_Float16)pw1[k * 256 + col];
    } else {            // pw2: 256x256, KS=8
        int o = idx - 16384;
        int j = o & 7, l = (o >> 3) & 63, ks = (o >> 9) & 7, ct = o >> 12;
        int k = 32 * ks + 8 * (l >> 4) + j;
        int col = 16 * ct + (l & 15);
        w2f[o] = (_Float16)pw2[k * 256 + col];
    }
    // warm rho/head weights into L3 so tail_kernel doesn't stream cold HBM
    float s = 0.f;
    if (idx < 32768) s += pw3[idx];
    if (idx < 32768) s += rw1[idx];
    if (idx < 65536) s += rw2[idx];
    if (idx < 32768) s += rw3[idx];
    if (idx < 36864) s += hw1[idx];
    if (idx < 65536) s += hw2[idx];
    if (idx < 1280)  s += hw3[idx];
    asm volatile("" :: "v"(s));
}

__device__ __forceinline__ void pin_reg(f16x8& v) {
    i32x4 t = __builtin_bit_cast(i32x4, v);
    asm volatile("" : "+v"(t));
    v = __builtin_bit_cast(f16x8, t);
}

// ---------------- fused phi + pool (persistent, 2 blocks/CU) -----------------
// 8 waves; wave w owns cols [32w, 32w+32) (2 ct), all 64 rows.
__global__ __attribute__((amdgpu_flat_work_group_size(512, 512), amdgpu_waves_per_eu(4, 4)))
void phi_kernel(
    const float* __restrict__ x,
    const float* __restrict__ pb1, const float* __restrict__ pb2,
    const _Float16* __restrict__ w1g, const _Float16* __restrict__ w2g,
    float* __restrict__ gsum, int ntiles) {
    __shared__ __align__(16) u16 xs[2][64 * 64];   // x fp16, swz ^((row&7)<<4), dbuf
    __shared__ __align__(16) u16 h1s[64 * 256];    // h1 fp16, swz ^((row&15)<<4), single
    __shared__ __align__(16) float b1s[256], b2s[256];

    const int tid = threadIdx.x;
    const int l = tid & 63;
    const int w = tid >> 6;
    const int fr = l & 15;
    const int fg = l >> 4;
    const int wb = w * 32;

    if (tid < 256) b1s[tid] = pb1[tid];
    else if (tid < 512) b2s[tid - 256] = pb2[tid - 256];

    // ---- weight fragments resident in VGPRs (80 regs), pinned
    f16x8 w1r[2][2];   // [ct][ks]
    f16x8 w2r[2][8];
#pragma unroll
    for (int ct = 0; ct < 2; ++ct) {
        int ctg = 2 * w + ct;
#pragma unroll
        for (int ks = 0; ks < 2; ++ks)
            w1r[ct][ks] = *(const f16x8*)(w1g + (((ctg << 1) + ks) << 9) + (l << 3));
#pragma unroll
        for (int ks = 0; ks < 8; ++ks)
            w2r[ct][ks] = *(const f16x8*)(w2g + (((ctg << 3) + ks) << 9) + (l << 3));
    }
#pragma unroll
    for (int ct = 0; ct < 2; ++ct) {
#pragma unroll
        for (int ks = 0; ks < 2; ++ks) pin_reg(w1r[ct][ks]);
#pragma unroll
        for (int ks = 0; ks < 8; ++ks) pin_reg(w2r[ct][ks]);
    }

    float psum[2][4] = {};

    const int t0 = blockIdx.x;
    // ---- prologue: stage tile t0 into xs[0]; prefetch t0+NBLK (as f16)
    {
        const float4* xg = (const float4*)(x + (size_t)t0 * 4096);
#pragma unroll
        for (int i = 0; i < 2; ++i) {
            int f4 = tid + i * 512;
            float4 v = xg[f4];
            int row = f4 >> 4, c4 = f4 & 15;
            f16x4 b;
            b[0] = (_Float16)v.x; b[1] = (_Float16)v.y;
            b[2] = (_Float16)v.z; b[3] = (_Float16)v.w;
            int byte = (row * 128 + c4 * 8) ^ ((row & 7) << 4);
            *(f16x4*)((char*)xs[0] + byte) = b;
        }
    }
    f16x4 pfh0, pfh1;
    {
        int tn = (t0 + NBLK < ntiles) ? t0 + NBLK : 0;
        const float4* xg = (const float4*)(x + (size_t)tn * 4096);
        float4 v0 = xg[tid], v1 = xg[tid + 512];
        pfh0[0] = (_Float16)v0.x; pfh0[1] = (_Float16)v0.y;
        pfh0[2] = (_Float16)v0.z; pfh0[3] = (_Float16)v0.w;
        pfh1[0] = (_Float16)v1.x; pfh1[1] = (_Float16)v1.y;
        pfh1[2] = (_Float16)v1.z; pfh1[3] = (_Float16)v1.w;
    }
    __syncthreads();

    int buf = 0;
    for (int t = t0; t < ntiles; t += NBLK) {
        // ---- GEMM1 (rt-outer, 8 live acc regs): h1 = relu(x@pw1+pb1)
#pragma unroll
        for (int rt = 0; rt < 4; ++rt) {
            f32x4 acc[2] = {};
#pragma unroll
            for (int ks = 0; ks < 2; ++ks) {
                int row = (rt << 4) + fr;
                int byte = ((row << 7) + (ks << 6) + (fg << 4)) ^ ((row & 7) << 4);
                f16x8 bd = *(const f16x8*)((char*)xs[buf] + byte);
#pragma unroll
                for (int ct = 0; ct < 2; ++ct)
                    acc[ct] = __builtin_amdgcn_mfma_f32_16x16x32_f16(w1r[ct][ks], bd, acc[ct], 0, 0, 0);
            }
#pragma unroll
            for (int ct = 0; ct < 2; ++ct) {
                int c0 = wb + 16 * ct + 4 * fg;
                f32x4 bb = *(const f32x4*)(b1s + c0);
                int rown = (rt << 4) + fr;
                f16x4 o;
                o[0] = (_Float16)fmaxf(acc[ct][0] + bb[0], 0.f);
                o[1] = (_Float16)fmaxf(acc[ct][1] + bb[1], 0.f);
                o[2] = (_Float16)fmaxf(acc[ct][2] + bb[2], 0.f);
                o[3] = (_Float16)fmaxf(acc[ct][3] + bb[3], 0.f);
                int byte = ((rown << 9) + (c0 << 1)) ^ ((rown & 15) << 4);
                *(f16x4*)((char*)h1s + byte) = o;
            }
        }
        // ---- stage next x tile (f16 regs -> xs[buf^1]); prefetch t+2*NBLK
#pragma unroll
        for (int i = 0; i < 2; ++i) {
            f16x4 b = i ? pfh1 : pfh0;
            int f4 = tid + i * 512;
            int row = f4 >> 4, c4 = f4 & 15;
            int byte = (row * 128 + c4 * 8) ^ ((row & 7) << 4);
            *(f16x4*)((char*)xs[buf ^ 1] + byte) = b;
        }
        {
            int tn = (t + 2 * NBLK < ntiles) ? t + 2 * NBLK : 0;
            const float4* xg = (const float4*)(x + (size_t)tn * 4096);
            float4 v0 = xg[tid], v1 = xg[tid + 512];
            pfh0[0] = (_Float16)v0.x; pfh0[1] = (_Float16)v0.y;
            pfh0[2] = (_Float16)v0.z; pfh0[3] = (_Float16)v0.w;
            pfh1[0] = (_Float16)v1.x; pfh1[1] = (_Float16)v1.y;
            pfh1[2] = (_Float16)v1.z; pfh1[3] = (_Float16)v1.w;
        }
        __syncthreads();   // h1s written by all waves; xs[buf^1] staged

        // ---- GEMM2 (rt-outer): pool relu(h1@pw2+pb2) into psum
#pragma unroll
        for (int rt = 0; rt < 4; ++rt) {
            f32x4 acc2[2] = {};
#pragma unroll
            for (int ks = 0; ks < 8; ++ks) {
                int row = (rt << 4) + fr;
                int byte = ((row << 9) + (ks << 6) + (fg << 4)) ^ ((row & 15) << 4);
                f16x8 bd = *(const f16x8*)((char*)h1s + byte);
#pragma unroll
                for (int ct = 0; ct < 2; ++ct)
                    acc2[ct] = __builtin_amdgcn_mfma_f32_16x16x32_f16(w2r[ct][ks], bd, acc2[ct], 0, 0, 0);
            }
#pragma unroll
            for (int ct = 0; ct < 2; ++ct) {
                int c0 = wb + 16 * ct + 4 * fg;
                f32x4 bb = *(const f32x4*)(b2s + c0);
#pragma unroll
                for (int r = 0; r < 4; ++r)
                    psum[ct][r] += fmaxf(acc2[ct][r] + bb[r], 0.f);
            }
        }
        __syncthreads();   // protect h1s (next GEMM1 write) + xs[buf] reads
        buf ^= 1;
    }

    // ---- final: reduce psum over the 16 fr-lanes, one atomicAdd per col
#pragma unroll
    for (int ct = 0; ct < 2; ++ct)
#pragma unroll
        for (int r = 0; r < 4; ++r) {
            float v = psum[ct][r];
            v += __shfl_xor(v, 1, 64);
            v += __shfl_xor(v, 2, 64);
            v += __shfl_xor(v, 4, 64);
            v += __shfl_xor(v, 8, 64);
            if (fr == 0) atomicAdd(&gsum[wb + ct * 16 + fg * 4 + r], v);
        }
}

// ---------------- tail: split-K parallel rho + head (fp32, 1024 threads) ----
__global__ __launch_bounds__(1024) void tail_kernel(
    const float* __restrict__ gsum, const float* __restrict__ xst,
    const float* __restrict__ pw3, const float* __restrict__ pb3,
    const float* __restrict__ rw1, const float* __restrict__ rb1,
    const float* __restrict__ rw2, const float* __restrict__ rb2,
    const float* __restrict__ rw3, const float* __restrict__ rb3,
    const float* __restrict__ w1, const float* __restrict__ b1,
    const float* __restrict__ w2, const float* __restrict__ b2,
    const float* __restrict__ w3, const float* __restrict__ b3,
    float* __restrict__ out, float nf) {
    __shared__ float fp[128], r1[256], r2[256], tc[144], t1[256], t2[256];
    __shared__ float part[8][256];
    const int t = threadIdx.x;

    {   // fp = nf*pb3 + gsum @ pw3  (256->128, 8-way)
        int j = t & 127, q = t >> 7;
        float s = 0.f;
        for (int i = 32 * q; i < 32 * q + 32; ++i) s += gsum[i] * pw3[i * 128 + j];
        part[q][j] = s;
    }
    __syncthreads();
    if (t < 128) { float s = nf * pb3[t]; for (int q = 0; q < 8; ++q) s += part[q][t]; fp[t] = s; }
    __syncthreads();
    {   // r1 = relu(fp @ rw1 + rb1)  (128->256, 4-way)
        int j = t & 255, q = t >> 8;
        float s = 0.f;
        for (int i = 32 * q; i < 32 * q + 32; ++i) s += fp[i] * rw1[i * 256 + j];
        part[q][j] = s;
    }
    __syncthreads();
    if (t < 256) { float s = rb1[t]; for (int q = 0; q < 4; ++q) s += part[q][t]; r1[t] = fmaxf(s, 0.f); }
    __syncthreads();
    {   // r2 = relu(r1 @ rw2 + rb2)  (256->256, 4-way)
        int j = t & 255, q = t >> 8;
        float s = 0.f;
        for (int i = 64 * q; i < 64 * q + 64; ++i) s += r1[i] * rw2[i * 256 + j];
        part[q][j] = s;
    }
    __syncthreads();
    if (t < 256) { float s = rb2[t]; for (int q = 0; q < 4; ++q) s += part[q][t]; r2[t] = fmaxf(s, 0.f); }
    __syncthreads();
    {   // tc[0:128] = r2 @ rw3 + rb3  (256->128, 8-way)
        int j = t & 127, q = t >> 7;
        float s = 0.f;
        for (int i = 32 * q; i < 32 * q + 32; ++i) s += r2[i] * rw3[i * 128 + j];
        part[q][j] = s;
    }
    __syncthreads();
    if (t < 128) { float s = rb3[t]; for (int q = 0; q < 8; ++q) s += part[q][t]; tc[t] = s; }
    else if (t < 144) tc[t] = xst[t - 128];
    __syncthreads();
    {   // t1 = relu(tc @ w1 + b1)  (144->256, 4-way, 36 each)
        int j = t & 255, q = t >> 8;
        float s = 0.f;
        for (int i = 36 * q; i < 36 * q + 36; ++i) s += tc[i] * w1[i * 256 + j];
        part[q][j] = s;
    }
    __syncthreads();
    if (t < 256) { float s = b1[t]; for (int q = 0; q < 4; ++q) s += part[q][t]; t1[t] = fmaxf(s, 0.f); }
    __syncthreads();
    {   // t2 = relu(t1 @ w2 + b2)  (256->256, 4-way)
        int j = t & 255, q = t >> 8;
        float s = 0.f;
        for (int i = 64 * q; i < 64 * q + 64; ++i) s += t1[i] * w2[i * 256 + j];
        part[q][j] = s;
    }
    __syncthreads();
    if (t < 256) { float s = b2[t]; for (int q = 0; q < 4; ++q) s += part[q][t]; t2[t] = fmaxf(s, 0.f); }
    __syncthreads();
    {   // out = t2 @ w3 + b3  (256->5, 4-way)
        int j = t & 255, q = t >> 8;
        if (j < 5) {
            float s = 0.f;
            for (int i = 64 * q; i < 64 * q + 64; ++i) s += t2[i] * w3[i * 5 + j];
            part[q][j] = s;
        }
    }
    __syncthreads();
    if (t < 5) { float s = b3[t]; for (int q = 0; q < 4; ++q) s += part[q][t]; out[t] = s; }
}

extern "C" void kernel_launch(void* const* d_in, const int* in_sizes, int n_in,
                              void* d_out, int out_size, void* d_ws, size_t ws_size,
                              hipStream_t stream) {
    (void)n_in; (void)out_size; (void)ws_size;
    const float* x   = (const float*)d_in[0];
    const float* xst = (const float*)d_in[1];
    const float* pw1 = (const float*)d_in[2];
    const float* pb1 = (const float*)d_in[3];
    const float* pw2 = (const float*)d_in[4];
    const float* pb2 = (const float*)d_in[5];
    const float* pw3 = (const float*)d_in[6];
    const float* pb3 = (const float*)d_in[7];
    const float* rw1 = (const float*)d_in[8];
    const float* rb1 = (const float*)d_in[9];
    const float* rw2 = (const float*)d_in[10];
    const float* rb2 = (const float*)d_in[11];
    const float* rw3 = (const float*)d_in[12];
    const float* rb3 = (const float*)d_in[13];
    const float* w1  = (const float*)d_in[14];
    const float* b1  = (const float*)d_in[15];
    const float* w2  = (const float*)d_in[16];
    const float* b2  = (const float*)d_in[17];
    const float* w3  = (const float*)d_in[18];
    const float* b3  = (const float*)d_in[19];
    float* out = (float*)d_out;

    int n = in_sizes[0] / 64;      // 400000
    int ntiles = n >> 6;           // 6250

    char* ws = (char*)d_ws;
    float* gsum = (float*)ws;                       // 256 f32 (1KB)
    _Float16* w1f = (_Float16*)(ws + 1024);         // 16384 f16 (32KB)
    _Float16* w2f = (_Float16*)(ws + 1024 + 32768); // 65536 f16 (128KB)

    prep_kernel<<<160, 512, 0, stream>>>(pw1, pw2, w1f, w2f, gsum,
                                         pw3, rw1, rw2, rw3, w1, w2, w3);
    phi_kernel<<<NBLK, 512, 0, stream>>>(x, pb1, pb2, w1f, w2f, gsum, ntiles);
    tail_kernel<<<1, 1024, 0, stream>>>(gsum, xst, pw3, pb3, rw1, rb1, rw2, rb2,
                                        rw3, rb3, w1, b1, w2, b2, w3, b3, out, (float)n);
}

// Round 9
// 141.888 us; speedup vs baseline: 2.0629x; 2.0629x over previous
//
#include <hip/hip_runtime.h>

// DeepSets fused kernel for MI355X (gfx950) — round 9.
// r8 failed: waves_per_eu(4,4) forced VGPR=64 -> weights spilled (FETCH 400MB).
// r9: r5's phi VERBATIM (proven 116 VGPR, no spill, 85.8us at 1 block/CU) with
// only: grid 256->512 (LDS 80KB = exactly 2 blocks/CU) and waves_per_eu(2,8)
// (min=2 keeps the 256-reg budget that produced 116 regs; max=8 lets HW
// co-schedule the 2nd block -> phases overlap). Keep r6's split-K tail + warm.

typedef unsigned short u16;
typedef _Float16 f16x8 __attribute__((ext_vector_type(8)));
typedef _Float16 f16x4 __attribute__((ext_vector_type(4)));
typedef float f32x4 __attribute__((ext_vector_type(4)));
typedef int i32x4 __attribute__((ext_vector_type(4)));

#define NBLK 512   // 2 blocks/CU (80KB LDS each)

// ---------------- prep: fp32 weights -> fp16 fragments, zero gsum, warm L3 ---
// Fragment layout (validated r1-r8): lane l, elem j holds W[k=32*ks+8*(l>>4)+j][16*ctg+(l&15)]
// at frag[((ctg*KS+ks)*64 + l)*8 + j]. Used as MFMA *A* operand: D = W^T X^T = (XW)^T.
__global__ void prep_kernel(const float* __restrict__ pw1, const float* __restrict__ pw2,
                            _Float16* __restrict__ w1f, _Float16* __restrict__ w2f,
                            float* __restrict__ gsum,
                            const float* __restrict__ pw3, const float* __restrict__ rw1,
                            const float* __restrict__ rw2, const float* __restrict__ rw3,
                            const float* __restrict__ hw1, const float* __restrict__ hw2,
                            const float* __restrict__ hw3) {
    int idx = blockIdx.x * blockDim.x + threadIdx.x;   // 160*512 = 81920
    if (idx < 256) gsum[idx] = 0.f;
    if (idx < 16384) {  // pw1: 64x256, KS=2
        int j = idx & 7, l = (idx >> 3) & 63, ks = (idx >> 9) & 1, ct = idx >> 10;
        int k = 32 * ks + 8 * (l >> 4) + j;
        int col = 16 * ct + (l & 15);
        w1f[idx] = (_Float16)pw1[k * 256 + col];
    } else {            // pw2: 256x256, KS=8
        int o = idx - 16384;
        int j = o & 7, l = (o >> 3) & 63, ks = (o >> 9) & 7, ct = o >> 12;
        int k = 32 * ks + 8 * (l >> 4) + j;
        int col = 16 * ct + (l & 15);
        w2f[o] = (_Float16)pw2[k * 256 + col];
    }
    // warm rho/head weights into L3 so tail_kernel doesn't stream cold HBM
    float s = 0.f;
    if (idx < 32768) s += pw3[idx];
    if (idx < 32768) s += rw1[idx];
    if (idx < 65536) s += rw2[idx];
    if (idx < 32768) s += rw3[idx];
    if (idx < 36864) s += hw1[idx];
    if (idx < 65536) s += hw2[idx];
    if (idx < 1280)  s += hw3[idx];
    asm volatile("" :: "v"(s));
}

__device__ __forceinline__ void pin_reg(f16x8& v) {
    i32x4 t = __builtin_bit_cast(i32x4, v);
    asm volatile("" : "+v"(t));
    v = __builtin_bit_cast(f16x8, t);
}

// ---------------- fused phi + pool (persistent, 2 blocks/CU) -----------------
// 8 waves; wave w owns cols [32w, 32w+32); dbuf xs + dbuf h1s, ONE barrier/iter.
__global__ __attribute__((amdgpu_flat_work_group_size(512, 512), amdgpu_waves_per_eu(2, 8)))
void phi_kernel(
    const float* __restrict__ x,
    const float* __restrict__ pb1, const float* __restrict__ pb2,
    const _Float16* __restrict__ w1g, const _Float16* __restrict__ w2g,
    float* __restrict__ gsum, int ntiles) {
    __shared__ __align__(16) u16 xs[2][64 * 64];    // x tile fp16, swz ^((row&7)<<4)
    __shared__ __align__(16) u16 h1s[2][64 * 256];  // h1 tile fp16, swz ^((row&15)<<4)

    const int tid = threadIdx.x;
    const int l = tid & 63;
    const int w = tid >> 6;
    const int fr = l & 15;
    const int fg = l >> 4;
    const int wb = w * 32;

    // ---- preload weight fragments into registers (loop-invariant, pinned)
    f16x8 w1r[2][2];   // [ct][ks]
#pragma unroll
    for (int ct = 0; ct < 2; ++ct)
#pragma unroll
        for (int ks = 0; ks < 2; ++ks) {
            int ctg = 2 * w + ct;
            w1r[ct][ks] = *(const f16x8*)(w1g + (((ctg << 1) + ks) << 9) + (l << 3));
        }
    f16x8 w2r[2][8];   // [ct][ks]
#pragma unroll
    for (int ct = 0; ct < 2; ++ct)
#pragma unroll
        for (int ks = 0; ks < 8; ++ks) {
            int ctg = 2 * w + ct;
            w2r[ct][ks] = *(const f16x8*)(w2g + (((ctg << 3) + ks) << 9) + (l << 3));
        }
#pragma unroll
    for (int ct = 0; ct < 2; ++ct) {
#pragma unroll
        for (int ks = 0; ks < 2; ++ks) pin_reg(w1r[ct][ks]);
#pragma unroll
        for (int ks = 0; ks < 8; ++ks) pin_reg(w2r[ct][ks]);
    }
    f32x4 b1v[2], b2v[2];
#pragma unroll
    for (int ct = 0; ct < 2; ++ct) {
        int c0 = wb + ct * 16 + fg * 4;
        b1v[ct] = *(const f32x4*)(pb1 + c0);
        b2v[ct] = *(const f32x4*)(pb2 + c0);
    }

    float psum[2][4] = {{0.f, 0.f, 0.f, 0.f}, {0.f, 0.f, 0.f, 0.f}};

    const int t0 = blockIdx.x;
    // ---- prologue: stage tile t0 into xs[0], prefetch t0+NBLK into regs
    {
        const float4* xg = (const float4*)(x + (size_t)t0 * 4096);
#pragma unroll
        for (int i = 0; i < 2; ++i) {
            int f4 = tid + i * 512;
            float4 v = xg[f4];
            int row = f4 >> 4, c4 = f4 & 15;
            f16x4 b;
            b[0] = (_Float16)v.x; b[1] = (_Float16)v.y;
            b[2] = (_Float16)v.z; b[3] = (_Float16)v.w;
            int byte = (row * 128 + c4 * 8) ^ ((row & 7) << 4);
            *(f16x4*)((char*)xs[0] + byte) = b;
        }
    }
    float4 pf0, pf1;
    {
        int tn = (t0 + NBLK < ntiles) ? t0 + NBLK : 0;
        const float4* xg = (const float4*)(x + (size_t)tn * 4096);
        pf0 = xg[tid];
        pf1 = xg[tid + 512];
    }
    __syncthreads();

    int buf = 0, hb = 0;
    for (int t = t0; t < ntiles; t += NBLK) {
        // ---- GEMM1: D1 = (x@pw1)^T from xs[buf]
        {
            f32x4 acc[2][4] = {};
#pragma unroll
            for (int ks = 0; ks < 2; ++ks) {
                f16x8 bd[4];
#pragma unroll
                for (int rt = 0; rt < 4; ++rt) {
                    int row = (rt << 4) + fr;
                    int byte = ((row << 7) + (ks << 6) + (fg << 4)) ^ ((row & 7) << 4);
                    bd[rt] = *(const f16x8*)((char*)xs[buf] + byte);
                }
#pragma unroll
                for (int ct = 0; ct < 2; ++ct)
#pragma unroll
                    for (int rt = 0; rt < 4; ++rt)
                        acc[ct][rt] = __builtin_amdgcn_mfma_f32_16x16x32_f16(w1r[ct][ks], bd[rt], acc[ct][rt], 0, 0, 0);
            }
            // epilogue: bias+relu; lane holds h-cols c0..c0+3 of row rown -> b64 write
#pragma unroll
            for (int ct = 0; ct < 2; ++ct) {
                int c0 = wb + ct * 16 + fg * 4;
#pragma unroll
                for (int rt = 0; rt < 4; ++rt) {
                    int rown = (rt << 4) + fr;
                    f16x4 o;
                    o[0] = (_Float16)fmaxf(acc[ct][rt][0] + b1v[ct][0], 0.f);
                    o[1] = (_Float16)fmaxf(acc[ct][rt][1] + b1v[ct][1], 0.f);
                    o[2] = (_Float16)fmaxf(acc[ct][rt][2] + b1v[ct][2], 0.f);
                    o[3] = (_Float16)fmaxf(acc[ct][rt][3] + b1v[ct][3], 0.f);
                    int byte = ((rown << 9) + (c0 << 1)) ^ ((rown & 15) << 4);
                    *(f16x4*)((char*)h1s[hb] + byte) = o;
                }
            }
        }
        // ---- stage next x tile (f16 regs -> xs[buf^1]); prefetch t+2*NBLK
#pragma unroll
        for (int i = 0; i < 2; ++i) {
            float4 v = i ? pf1 : pf0;
            int f4 = tid + i * 512;
            int row = f4 >> 4, c4 = f4 & 15;
            f16x4 b;
            b[0] = (_Float16)v.x; b[1] = (_Float16)v.y;
            b[2] = (_Float16)v.z; b[3] = (_Float16)v.w;
            int byte = (row * 128 + c4 * 8) ^ ((row & 7) << 4);
            *(f16x4*)((char*)xs[buf ^ 1] + byte) = b;
        }
        {
            int tn = (t + 2 * NBLK < ntiles) ? t + 2 * NBLK : 0;
            const float4* xg = (const float4*)(x + (size_t)tn * 4096);
            pf0 = xg[tid];
            pf1 = xg[tid + 512];
        }
        __syncthreads();   // h1s[hb] + xs[buf^1] now visible

        // ---- GEMM2: D2 = (h1@pw2)^T, pool into psum
        {
            f32x4 acc2[2][4] = {};
#pragma unroll
            for (int ks = 0; ks < 8; ++ks) {
                f16x8 bd[4];
#pragma unroll
                for (int rt = 0; rt < 4; ++rt) {
                    int row = (rt << 4) + fr;
                    int byte = ((row << 9) + (ks << 6) + (fg << 4)) ^ ((row & 15) << 4);
                    bd[rt] = *(const f16x8*)((char*)h1s[hb] + byte);
                }
#pragma unroll
                for (int ct = 0; ct < 2; ++ct)
#pragma unroll
                    for (int rt = 0; rt < 4; ++rt)
                        acc2[ct][rt] = __builtin_amdgcn_mfma_f32_16x16x32_f16(w2r[ct][ks], bd[rt], acc2[ct][rt], 0, 0, 0);
            }
#pragma unroll
            for (int ct = 0; ct < 2; ++ct)
#pragma unroll
                for (int r = 0; r < 4; ++r) {
                    float v = 0.f;
#pragma unroll
                    for (int rt = 0; rt < 4; ++rt)
                        v += fmaxf(acc2[ct][rt][r] + b2v[ct][r], 0.f);
                    psum[ct][r] += v;
                }
        }
        buf ^= 1;
        hb ^= 1;
    }

    // ---- final: reduce psum over the 16 fr-lanes, one atomicAdd per col
#pragma unroll
    for (int ct = 0; ct < 2; ++ct)
#pragma unroll
        for (int r = 0; r < 4; ++r) {
            float v = psum[ct][r];
            v += __shfl_xor(v, 1, 64);
            v += __shfl_xor(v, 2, 64);
            v += __shfl_xor(v, 4, 64);
            v += __shfl_xor(v, 8, 64);
            if (fr == 0) atomicAdd(&gsum[wb + ct * 16 + fg * 4 + r], v);
        }
}

// ---------------- tail: split-K parallel rho + head (fp32, 1024 threads) ----
__global__ __launch_bounds__(1024) void tail_kernel(
    const float* __restrict__ gsum, const float* __restrict__ xst,
    const float* __restrict__ pw3, const float* __restrict__ pb3,
    const float* __restrict__ rw1, const float* __restrict__ rb1,
    const float* __restrict__ rw2, const float* __restrict__ rb2,
    const float* __restrict__ rw3, const float* __restrict__ rb3,
    const float* __restrict__ w1, const float* __restrict__ b1,
    const float* __restrict__ w2, const float* __restrict__ b2,
    const float* __restrict__ w3, const float* __restrict__ b3,
    float* __restrict__ out, float nf) {
    __shared__ float fp[128], r1[256], r2[256], tc[144], t1[256], t2[256];
    __shared__ float part[8][256];
    const int t = threadIdx.x;

    {   // fp = nf*pb3 + gsum @ pw3  (256->128, 8-way)
        int j = t & 127, q = t >> 7;
        float s = 0.f;
        for (int i = 32 * q; i < 32 * q + 32; ++i) s += gsum[i] * pw3[i * 128 + j];
        part[q][j] = s;
    }
    __syncthreads();
    if (t < 128) { float s = nf * pb3[t]; for (int q = 0; q < 8; ++q) s += part[q][t]; fp[t] = s; }
    __syncthreads();
    {   // r1 = relu(fp @ rw1 + rb1)  (128->256, 4-way)
        int j = t & 255, q = t >> 8;
        float s = 0.f;
        for (int i = 32 * q; i < 32 * q + 32; ++i) s += fp[i] * rw1[i * 256 + j];
        part[q][j] = s;
    }
    __syncthreads();
    if (t < 256) { float s = rb1[t]; for (int q = 0; q < 4; ++q) s += part[q][t]; r1[t] = fmaxf(s, 0.f); }
    __syncthreads();
    {   // r2 = relu(r1 @ rw2 + rb2)  (256->256, 4-way)
        int j = t & 255, q = t >> 8;
        float s = 0.f;
        for (int i = 64 * q; i < 64 * q + 64; ++i) s += r1[i] * rw2[i * 256 + j];
        part[q][j] = s;
    }
    __syncthreads();
    if (t < 256) { float s = rb2[t]; for (int q = 0; q < 4; ++q) s += part[q][t]; r2[t] = fmaxf(s, 0.f); }
    __syncthreads();
    {   // tc[0:128] = r2 @ rw3 + rb3  (256->128, 8-way)
        int j = t & 127, q = t >> 7;
        float s = 0.f;
        for (int i = 32 * q; i < 32 * q + 32; ++i) s += r2[i] * rw3[i * 128 + j];
        part[q][j] = s;
    }
    __syncthreads();
    if (t < 128) { float s = rb3[t]; for (int q = 0; q < 8; ++q) s += part[q][t]; tc[t] = s; }
    else if (t < 144) tc[t] = xst[t - 128];
    __syncthreads();
    {   // t1 = relu(tc @ w1 + b1)  (144->256, 4-way, 36 each)
        int j = t & 255, q = t >> 8;
        float s = 0.f;
        for (int i = 36 * q; i < 36 * q + 36; ++i) s += tc[i] * w1[i * 256 + j];
        part[q][j] = s;
    }
    __syncthreads();
    if (t < 256) { float s = b1[t]; for (int q = 0; q < 4; ++q) s += part[q][t]; t1[t] = fmaxf(s, 0.f); }
    __syncthreads();
    {   // t2 = relu(t1 @ w2 + b2)  (256->256, 4-way)
        int j = t & 255, q = t >> 8;
        float s = 0.f;
        for (int i = 64 * q; i < 64 * q + 64; ++i) s += t1[i] * w2[i * 256 + j];
        part[q][j] = s;
    }
    __syncthreads();
    if (t < 256) { float s = b2[t]; for (int q = 0; q < 4; ++q) s += part[q][t]; t2[t] = fmaxf(s, 0.f); }
    __syncthreads();
    {   // out = t2 @ w3 + b3  (256->5, 4-way)
        int j = t & 255, q = t >> 8;
        if (j < 5) {
            float s = 0.f;
            for (int i = 64 * q; i < 64 * q + 64; ++i) s += t2[i] * w3[i * 5 + j];
            part[q][j] = s;
        }
    }
    __syncthreads();
    if (t < 5) { float s = b3[t]; for (int q = 0; q < 4; ++q) s += part[q][t]; out[t] = s; }
}

extern "C" void kernel_launch(void* const* d_in, const int* in_sizes, int n_in,
                              void* d_out, int out_size, void* d_ws, size_t ws_size,
                              hipStream_t stream) {
    (void)n_in; (void)out_size; (void)ws_size;
    const float* x   = (const float*)d_in[0];
    const float* xst = (const float*)d_in[1];
    const float* pw1 = (const float*)d_in[2];
    const float* pb1 = (const float*)d_in[3];
    const float* pw2 = (const float*)d_in[4];
    const float* pb2 = (const float*)d_in[5];
    const float* pw3 = (const float*)d_in[6];
    const float* pb3 = (const float*)d_in[7];
    const float* rw1 = (const float*)d_in[8];
    const float* rb1 = (const float*)d_in[9];
    const float* rw2 = (const float*)d_in[10];
    const float* rb2 = (const float*)d_in[11];
    const float* rw3 = (const float*)d_in[12];
    const float* rb3 = (const float*)d_in[13];
    const float* w1  = (const float*)d_in[14];
    const float* b1  = (const float*)d_in[15];
    const float* w2  = (const float*)d_in[16];
    const float* b2  = (const float*)d_in[17];
    const float* w3  = (const float*)d_in[18];
    const float* b3  = (const float*)d_in[19];
    float* out = (float*)d_out;

    int n = in_sizes[0] / 64;      // 400000
    int ntiles = n >> 6;           // 6250

    char* ws = (char*)d_ws;
    float* gsum = (float*)ws;                       // 256 f32 (1KB)
    _Float16* w1f = (_Float16*)(ws + 1024);         // 16384 f16 (32KB)
    _Float16* w2f = (_Float16*)(ws + 1024 + 32768); // 65536 f16 (128KB)

    prep_kernel<<<160, 512, 0, stream>>>(pw1, pw2, w1f, w2f, gsum,
                                         pw3, rw1, rw2, rw3, w1, w2, w3);
    phi_kernel<<<NBLK, 512, 0, stream>>>(x, pb1, pb2, w1f, w2f, gsum, ntiles);
    tail_kernel<<<1, 1024, 0, stream>>>(gsum, xst, pw3, pb3, rw1, rb1, rw2, rb2,
                                        rw3, rb3, w1, b1, w2, b2, w3, b3, out, (float)n);
}

// Round 10
// 138.655 us; speedup vs baseline: 2.1110x; 1.0233x over previous
//
#include <hip/hip_runtime.h>

// DeepSets fused kernel for MI355X (gfx950) — round 10.
// r9: 2x80KB LDS did NOT co-schedule (occupancy stuck 19.6%, phi 104us) ->
// usable LDS/CU for packing is < 160KB. r10: single-buffer h1s -> 48KB LDS
// (2 blocks/CU by LDS; VGPR 112 -> 4 waves/SIMD tier = 16 waves/CU = 2 blocks).
// Same register structure as r5/r9 (proven 112 regs, no spill), two barriers
// per iter. Keep split-K tail + L3 warm.

typedef unsigned short u16;
typedef _Float16 f16x8 __attribute__((ext_vector_type(8)));
typedef _Float16 f16x4 __attribute__((ext_vector_type(4)));
typedef float f32x4 __attribute__((ext_vector_type(4)));
typedef int i32x4 __attribute__((ext_vector_type(4)));

#define NBLK 512   // 2 blocks/CU

// ---------------- prep: fp32 weights -> fp16 fragments, zero gsum, warm L3 ---
// Fragment layout (validated r1-r9): lane l, elem j holds W[k=32*ks+8*(l>>4)+j][16*ctg+(l&15)]
// at frag[((ctg*KS+ks)*64 + l)*8 + j]. Used as MFMA *A* operand: D = W^T X^T = (XW)^T.
__global__ void prep_kernel(const float* __restrict__ pw1, const float* __restrict__ pw2,
                            _Float16* __restrict__ w1f, _Float16* __restrict__ w2f,
                            float* __restrict__ gsum,
                            const float* __restrict__ pw3, const float* __restrict__ rw1,
                            const float* __restrict__ rw2, const float* __restrict__ rw3,
                            const float* __restrict__ hw1, const float* __restrict__ hw2,
                            const float* __restrict__ hw3) {
    int idx = blockIdx.x * blockDim.x + threadIdx.x;   // 160*512 = 81920
    if (idx < 256) gsum[idx] = 0.f;
    if (idx < 16384) {  // pw1: 64x256, KS=2
        int j = idx & 7, l = (idx >> 3) & 63, ks = (idx >> 9) & 1, ct = idx >> 10;
        int k = 32 * ks + 8 * (l >> 4) + j;
        int col = 16 * ct + (l & 15);
        w1f[idx] = (_Float16)pw1[k * 256 + col];
    } else {            // pw2: 256x256, KS=8
        int o = idx - 16384;
        int j = o & 7, l = (o >> 3) & 63, ks = (o >> 9) & 7, ct = o >> 12;
        int k = 32 * ks + 8 * (l >> 4) + j;
        int col = 16 * ct + (l & 15);
        w2f[o] = (_Float16)pw2[k * 256 + col];
    }
    // warm rho/head weights into L3 so tail_kernel doesn't stream cold HBM
    float s = 0.f;
    if (idx < 32768) s += pw3[idx];
    if (idx < 32768) s += rw1[idx];
    if (idx < 65536) s += rw2[idx];
    if (idx < 32768) s += rw3[idx];
    if (idx < 36864) s += hw1[idx];
    if (idx < 65536) s += hw2[idx];
    if (idx < 1280)  s += hw3[idx];
    asm volatile("" :: "v"(s));
}

__device__ __forceinline__ void pin_reg(f16x8& v) {
    i32x4 t = __builtin_bit_cast(i32x4, v);
    asm volatile("" : "+v"(t));
    v = __builtin_bit_cast(f16x8, t);
}

// ---------------- fused phi + pool (persistent, 2 blocks/CU) -----------------
// 8 waves; wave w owns cols [32w, 32w+32); dbuf xs (16KB) + single h1s (32KB).
__global__ __attribute__((amdgpu_flat_work_group_size(512, 512), amdgpu_waves_per_eu(2, 8)))
void phi_kernel(
    const float* __restrict__ x,
    const float* __restrict__ pb1, const float* __restrict__ pb2,
    const _Float16* __restrict__ w1g, const _Float16* __restrict__ w2g,
    float* __restrict__ gsum, int ntiles) {
    __shared__ __align__(16) u16 xs[2][64 * 64];   // x tile fp16, swz ^((row&7)<<4)
    __shared__ __align__(16) u16 h1s[64 * 256];    // h1 tile fp16, swz ^((row&15)<<4)

    const int tid = threadIdx.x;
    const int l = tid & 63;
    const int w = tid >> 6;
    const int fr = l & 15;
    const int fg = l >> 4;
    const int wb = w * 32;

    // ---- preload weight fragments into registers (loop-invariant, pinned)
    f16x8 w1r[2][2];   // [ct][ks]
#pragma unroll
    for (int ct = 0; ct < 2; ++ct)
#pragma unroll
        for (int ks = 0; ks < 2; ++ks) {
            int ctg = 2 * w + ct;
            w1r[ct][ks] = *(const f16x8*)(w1g + (((ctg << 1) + ks) << 9) + (l << 3));
        }
    f16x8 w2r[2][8];   // [ct][ks]
#pragma unroll
    for (int ct = 0; ct < 2; ++ct)
#pragma unroll
        for (int ks = 0; ks < 8; ++ks) {
            int ctg = 2 * w + ct;
            w2r[ct][ks] = *(const f16x8*)(w2g + (((ctg << 3) + ks) << 9) + (l << 3));
        }
#pragma unroll
    for (int ct = 0; ct < 2; ++ct) {
#pragma unroll
        for (int ks = 0; ks < 2; ++ks) pin_reg(w1r[ct][ks]);
#pragma unroll
        for (int ks = 0; ks < 8; ++ks) pin_reg(w2r[ct][ks]);
    }
    f32x4 b1v[2], b2v[2];
#pragma unroll
    for (int ct = 0; ct < 2; ++ct) {
        int c0 = wb + ct * 16 + fg * 4;
        b1v[ct] = *(const f32x4*)(pb1 + c0);
        b2v[ct] = *(const f32x4*)(pb2 + c0);
    }

    float psum[2][4] = {{0.f, 0.f, 0.f, 0.f}, {0.f, 0.f, 0.f, 0.f}};

    const int t0 = blockIdx.x;
    // ---- prologue: stage tile t0 into xs[0], prefetch t0+NBLK into regs
    {
        const float4* xg = (const float4*)(x + (size_t)t0 * 4096);
#pragma unroll
        for (int i = 0; i < 2; ++i) {
            int f4 = tid + i * 512;
            float4 v = xg[f4];
            int row = f4 >> 4, c4 = f4 & 15;
            f16x4 b;
            b[0] = (_Float16)v.x; b[1] = (_Float16)v.y;
            b[2] = (_Float16)v.z; b[3] = (_Float16)v.w;
            int byte = (row * 128 + c4 * 8) ^ ((row & 7) << 4);
            *(f16x4*)((char*)xs[0] + byte) = b;
        }
    }
    float4 pf0, pf1;
    {
        int tn = (t0 + NBLK < ntiles) ? t0 + NBLK : 0;
        const float4* xg = (const float4*)(x + (size_t)tn * 4096);
        pf0 = xg[tid];
        pf1 = xg[tid + 512];
    }
    __syncthreads();

    int buf = 0;
    for (int t = t0; t < ntiles; t += NBLK) {
        // ---- GEMM1: D1 = (x@pw1)^T from xs[buf] -> h1s
        {
            f32x4 acc[2][4] = {};
#pragma unroll
            for (int ks = 0; ks < 2; ++ks) {
                f16x8 bd[4];
#pragma unroll
                for (int rt = 0; rt < 4; ++rt) {
                    int row = (rt << 4) + fr;
                    int byte = ((row << 7) + (ks << 6) + (fg << 4)) ^ ((row & 7) << 4);
                    bd[rt] = *(const f16x8*)((char*)xs[buf] + byte);
                }
#pragma unroll
                for (int ct = 0; ct < 2; ++ct)
#pragma unroll
                    for (int rt = 0; rt < 4; ++rt)
                        acc[ct][rt] = __builtin_amdgcn_mfma_f32_16x16x32_f16(w1r[ct][ks], bd[rt], acc[ct][rt], 0, 0, 0);
            }
            // epilogue: bias+relu; lane holds h-cols c0..c0+3 of row rown -> b64 write
#pragma unroll
            for (int ct = 0; ct < 2; ++ct) {
                int c0 = wb + ct * 16 + fg * 4;
#pragma unroll
                for (int rt = 0; rt < 4; ++rt) {
                    int rown = (rt << 4) + fr;
                    f16x4 o;
                    o[0] = (_Float16)fmaxf(acc[ct][rt][0] + b1v[ct][0], 0.f);
                    o[1] = (_Float16)fmaxf(acc[ct][rt][1] + b1v[ct][1], 0.f);
                    o[2] = (_Float16)fmaxf(acc[ct][rt][2] + b1v[ct][2], 0.f);
                    o[3] = (_Float16)fmaxf(acc[ct][rt][3] + b1v[ct][3], 0.f);
                    int byte = ((rown << 9) + (c0 << 1)) ^ ((rown & 15) << 4);
                    *(f16x4*)((char*)h1s + byte) = o;
                }
            }
        }
        // ---- stage next x tile (f16 regs -> xs[buf^1]); prefetch t+2*NBLK
#pragma unroll
        for (int i = 0; i < 2; ++i) {
            float4 v = i ? pf1 : pf0;
            int f4 = tid + i * 512;
            int row = f4 >> 4, c4 = f4 & 15;
            f16x4 b;
            b[0] = (_Float16)v.x; b[1] = (_Float16)v.y;
            b[2] = (_Float16)v.z; b[3] = (_Float16)v.w;
            int byte = (row * 128 + c4 * 8) ^ ((row & 7) << 4);
            *(f16x4*)((char*)xs[buf ^ 1] + byte) = b;
        }
        {
            int tn = (t + 2 * NBLK < ntiles) ? t + 2 * NBLK : 0;
            const float4* xg = (const float4*)(x + (size_t)tn * 4096);
            pf0 = xg[tid];
            pf1 = xg[tid + 512];
        }
        __syncthreads();   // h1s complete + xs[buf^1] staged

        // ---- GEMM2: D2 = (h1@pw2)^T, pool into psum
        {
            f32x4 acc2[2][4] = {};
#pragma unroll
            for (int ks = 0; ks < 8; ++ks) {
                f16x8 bd[4];
#pragma unroll
                for (int rt = 0; rt < 4; ++rt) {
                    int row = (rt << 4) + fr;
                    int byte = ((row << 9) + (ks << 6) + (fg << 4)) ^ ((row & 15) << 4);
                    bd[rt] = *(const f16x8*)((char*)h1s + byte);
                }
#pragma unroll
                for (int ct = 0; ct < 2; ++ct)
#pragma unroll
                    for (int rt = 0; rt < 4; ++rt)
                        acc2[ct][rt] = __builtin_amdgcn_mfma_f32_16x16x32_f16(w2r[ct][ks], bd[rt], acc2[ct][rt], 0, 0, 0);
            }
#pragma unroll
            for (int ct = 0; ct < 2; ++ct)
#pragma unroll
                for (int r = 0; r < 4; ++r) {
                    float v = 0.f;
#pragma unroll
                    for (int rt = 0; rt < 4; ++rt)
                        v += fmaxf(acc2[ct][rt][r] + b2v[ct][r], 0.f);
                    psum[ct][r] += v;
                }
        }
        __syncthreads();   // protect h1s before next GEMM1 overwrite
        buf ^= 1;
    }

    // ---- final: reduce psum over the 16 fr-lanes, one atomicAdd per col
#pragma unroll
    for (int ct = 0; ct < 2; ++ct)
#pragma unroll
        for (int r = 0; r < 4; ++r) {
            float v = psum[ct][r];
            v += __shfl_xor(v, 1, 64);
            v += __shfl_xor(v, 2, 64);
            v += __shfl_xor(v, 4, 64);
            v += __shfl_xor(v, 8, 64);
            if (fr == 0) atomicAdd(&gsum[wb + ct * 16 + fg * 4 + r], v);
        }
}

// ---------------- tail: split-K parallel rho + head (fp32, 1024 threads) ----
__global__ __launch_bounds__(1024) void tail_kernel(
    const float* __restrict__ gsum, const float* __restrict__ xst,
    const float* __restrict__ pw3, const float* __restrict__ pb3,
    const float* __restrict__ rw1, const float* __restrict__ rb1,
    const float* __restrict__ rw2, const float* __restrict__ rb2,
    const float* __restrict__ rw3, const float* __restrict__ rb3,
    const float* __restrict__ w1, const float* __restrict__ b1,
    const float* __restrict__ w2, const float* __restrict__ b2,
    const float* __restrict__ w3, const float* __restrict__ b3,
    float* __restrict__ out, float nf) {
    __shared__ float fp[128], r1[256], r2[256], tc[144], t1[256], t2[256];
    __shared__ float part[8][256];
    const int t = threadIdx.x;

    {   // fp = nf*pb3 + gsum @ pw3  (256->128, 8-way)
        int j = t & 127, q = t >> 7;
        float s = 0.f;
        for (int i = 32 * q; i < 32 * q + 32; ++i) s += gsum[i] * pw3[i * 128 + j];
        part[q][j] = s;
    }
    __syncthreads();
    if (t < 128) { float s = nf * pb3[t]; for (int q = 0; q < 8; ++q) s += part[q][t]; fp[t] = s; }
    __syncthreads();
    {   // r1 = relu(fp @ rw1 + rb1)  (128->256, 4-way)
        int j = t & 255, q = t >> 8;
        float s = 0.f;
        for (int i = 32 * q; i < 32 * q + 32; ++i) s += fp[i] * rw1[i * 256 + j];
        part[q][j] = s;
    }
    __syncthreads();
    if (t < 256) { float s = rb1[t]; for (int q = 0; q < 4; ++q) s += part[q][t]; r1[t] = fmaxf(s, 0.f); }
    __syncthreads();
    {   // r2 = relu(r1 @ rw2 + rb2)  (256->256, 4-way)
        int j = t & 255, q = t >> 8;
        float s = 0.f;
        for (int i = 64 * q; i < 64 * q + 64; ++i) s += r1[i] * rw2[i * 256 + j];
        part[q][j] = s;
    }
    __syncthreads();
    if (t < 256) { float s = rb2[t]; for (int q = 0; q < 4; ++q) s += part[q][t]; r2[t] = fmaxf(s, 0.f); }
    __syncthreads();
    {   // tc[0:128] = r2 @ rw3 + rb3  (256->128, 8-way)
        int j = t & 127, q = t >> 7;
        float s = 0.f;
        for (int i = 32 * q; i < 32 * q + 32; ++i) s += r2[i] * rw3[i * 128 + j];
        part[q][j] = s;
    }
    __syncthreads();
    if (t < 128) { float s = rb3[t]; for (int q = 0; q < 8; ++q) s += part[q][t]; tc[t] = s; }
    else if (t < 144) tc[t] = xst[t - 128];
    __syncthreads();
    {   // t1 = relu(tc @ w1 + b1)  (144->256, 4-way, 36 each)
        int j = t & 255, q = t >> 8;
        float s = 0.f;
        for (int i = 36 * q; i < 36 * q + 36; ++i) s += tc[i] * w1[i * 256 + j];
        part[q][j] = s;
    }
    __syncthreads();
    if (t < 256) { float s = b1[t]; for (int q = 0; q < 4; ++q) s += part[q][t]; t1[t] = fmaxf(s, 0.f); }
    __syncthreads();
    {   // t2 = relu(t1 @ w2 + b2)  (256->256, 4-way)
        int j = t & 255, q = t >> 8;
        float s = 0.f;
        for (int i = 64 * q; i < 64 * q + 64; ++i) s += t1[i] * w2[i * 256 + j];
        part[q][j] = s;
    }
    __syncthreads();
    if (t < 256) { float s = b2[t]; for (int q = 0; q < 4; ++q) s += part[q][t]; t2[t] = fmaxf(s, 0.f); }
    __syncthreads();
    {   // out = t2 @ w3 + b3  (256->5, 4-way)
        int j = t & 255, q = t >> 8;
        if (j < 5) {
            float s = 0.f;
            for (int i = 64 * q; i < 64 * q + 64; ++i) s += t2[i] * w3[i * 5 + j];
            part[q][j] = s;
        }
    }
    __syncthreads();
    if (t < 5) { float s = b3[t]; for (int q = 0; q < 4; ++q) s += part[q][t]; out[t] = s; }
}

extern "C" void kernel_launch(void* const* d_in, const int* in_sizes, int n_in,
                              void* d_out, int out_size, void* d_ws, size_t ws_size,
                              hipStream_t stream) {
    (void)n_in; (void)out_size; (void)ws_size;
    const float* x   = (const float*)d_in[0];
    const float* xst = (const float*)d_in[1];
    const float* pw1 = (const float*)d_in[2];
    const float* pb1 = (const float*)d_in[3];
    const float* pw2 = (const float*)d_in[4];
    const float* pb2 = (const float*)d_in[5];
    const float* pw3 = (const float*)d_in[6];
    const float* pb3 = (const float*)d_in[7];
    const float* rw1 = (const float*)d_in[8];
    const float* rb1 = (const float*)d_in[9];
    const float* rw2 = (const float*)d_in[10];
    const float* rb2 = (const float*)d_in[11];
    const float* rw3 = (const float*)d_in[12];
    const float* rb3 = (const float*)d_in[13];
    const float* w1  = (const float*)d_in[14];
    const float* b1  = (const float*)d_in[15];
    const float* w2  = (const float*)d_in[16];
    const float* b2  = (const float*)d_in[17];
    const float* w3  = (const float*)d_in[18];
    const float* b3  = (const float*)d_in[19];
    float* out = (float*)d_out;

    int n = in_sizes[0] / 64;      // 400000
    int ntiles = n >> 6;           // 6250

    char* ws = (char*)d_ws;
    float* gsum = (float*)ws;                       // 256 f32 (1KB)
    _Float16* w1f = (_Float16*)(ws + 1024);         // 16384 f16 (32KB)
    _Float16* w2f = (_Float16*)(ws + 1024 + 32768); // 65536 f16 (128KB)

    prep_kernel<<<160, 512, 0, stream>>>(pw1, pw2, w1f, w2f, gsum,
                                         pw3, rw1, rw2, rw3, w1, w2, w3);
    phi_kernel<<<NBLK, 512, 0, stream>>>(x, pb1, pb2, w1f, w2f, gsum, ntiles);
    tail_kernel<<<1, 1024, 0, stream>>>(gsum, xst, pw3, pb3, rw1, rb1, rw2, rb2,
                                        rw3, rb3, w1, b1, w2, b2, w3, b3, out, (float)n);
}

// Round 11
// 132.910 us; speedup vs baseline: 2.2022x; 1.0432x over previous
//
#include <hip/hip_runtime.h>

// DeepSets fused kernel for MI355X (gfx950) — round 11.
// r5-r10 established: unified VGPR+AGPR file => ~180 regs/wave total => 2
// waves/SIMD ceiling; 2 blocks/CU unreachable with weights resident. So:
// producer/consumer wave specialization INSIDE the one resident block.
// Waves 0-3 (G1): GEMM1 for tile t   (w1 slice: 64 cols, 32 regs).
// Waves 4-7 (G2): GEMM2+pool tile t-1 (w2 slice: 64 cols, 128 regs).
// Disjoint role branches (duplicated loops, equal barrier counts) so the
// allocator overlays w1r/w2r. One barrier/iter, h1 double-buffered (80KB LDS).
// SIMD s hosts G1 wave s and G2 wave s => roles co-execute per SIMD.

typedef unsigned short u16;
typedef _Float16 f16x8 __attribute__((ext_vector_type(8)));
typedef _Float16 f16x4 __attribute__((ext_vector_type(4)));
typedef float f32x4 __attribute__((ext_vector_type(4)));
typedef int i32x4 __attribute__((ext_vector_type(4)));

#define NBLK 256

// ---------------- prep: fp32 weights -> fp16 fragments, zero gsum, warm L3 ---
// Fragment layout (validated r1-r10): lane l, elem j holds W[k=32*ks+8*(l>>4)+j][16*ctg+(l&15)]
// at frag[((ctg*KS+ks)*64 + l)*8 + j]. Used as MFMA *A* operand: D = W^T X^T = (XW)^T.
__global__ void prep_kernel(const float* __restrict__ pw1, const float* __restrict__ pw2,
                            _Float16* __restrict__ w1f, _Float16* __restrict__ w2f,
                            float* __restrict__ gsum,
                            const float* __restrict__ pw3, const float* __restrict__ rw1,
                            const float* __restrict__ rw2, const float* __restrict__ rw3,
                            const float* __restrict__ hw1, const float* __restrict__ hw2,
                            const float* __restrict__ hw3) {
    int idx = blockIdx.x * blockDim.x + threadIdx.x;   // 160*512 = 81920
    if (idx < 256) gsum[idx] = 0.f;
    if (idx < 16384) {  // pw1: 64x256, KS=2
        int j = idx & 7, l = (idx >> 3) & 63, ks = (idx >> 9) & 1, ct = idx >> 10;
        int k = 32 * ks + 8 * (l >> 4) + j;
        int col = 16 * ct + (l & 15);
        w1f[idx] = (_Float16)pw1[k * 256 + col];
    } else {            // pw2: 256x256, KS=8
        int o = idx - 16384;
        int j = o & 7, l = (o >> 3) & 63, ks = (o >> 9) & 7, ct = o >> 12;
        int k = 32 * ks + 8 * (l >> 4) + j;
        int col = 16 * ct + (l & 15);
        w2f[o] = (_Float16)pw2[k * 256 + col];
    }
    // warm rho/head weights into L3 so tail_kernel doesn't stream cold HBM
    float s = 0.f;
    if (idx < 32768) s += pw3[idx];
    if (idx < 32768) s += rw1[idx];
    if (idx < 65536) s += rw2[idx];
    if (idx < 32768) s += rw3[idx];
    if (idx < 36864) s += hw1[idx];
    if (idx < 65536) s += hw2[idx];
    if (idx < 1280)  s += hw3[idx];
    asm volatile("" :: "v"(s));
}

__device__ __forceinline__ void pin_reg(f16x8& v) {
    i32x4 t = __builtin_bit_cast(i32x4, v);
    asm volatile("" : "+v"(t));
    v = __builtin_bit_cast(f16x8, t);
}

// stage xs[dst] from pf regs + prefetch pf for tile tn
#define STAGE_AND_PREFETCH(DSTBUF, IT)                                         \
    {                                                                          \
        _Pragma("unroll")                                                      \
        for (int i = 0; i < 2; ++i) {                                          \
            float4 v = i ? pf1 : pf0;                                          \
            int f4 = tid + i * 512;                                            \
            int srow = f4 >> 4, c4 = f4 & 15;                                  \
            f16x4 b;                                                           \
            b[0] = (_Float16)v.x; b[1] = (_Float16)v.y;                        \
            b[2] = (_Float16)v.z; b[3] = (_Float16)v.w;                        \
            int sbyte = (srow * 128 + c4 * 8) ^ ((srow & 7) << 4);             \
            *(f16x4*)((char*)xs[DSTBUF] + sbyte) = b;                          \
        }                                                                      \
        int tn = t0 + ((IT) + 2) * NBLK;                                       \
        if (tn >= ntiles) tn = 0;                                              \
        const float4* xg = (const float4*)(x + (size_t)tn * 4096);             \
        pf0 = xg[tid];                                                         \
        pf1 = xg[tid + 512];                                                   \
    }

// ---------------- fused phi + pool (persistent, producer/consumer) ----------
__global__ __attribute__((amdgpu_flat_work_group_size(512, 512), amdgpu_waves_per_eu(2, 2)))
void phi_kernel(
    const float* __restrict__ x,
    const float* __restrict__ pb1, const float* __restrict__ pb2,
    const _Float16* __restrict__ w1g, const _Float16* __restrict__ w2g,
    float* __restrict__ gsum, int ntiles) {
    __shared__ __align__(16) u16 xs[2][64 * 64];    // x tile fp16, swz ^((row&7)<<4)
    __shared__ __align__(16) u16 h1s[2][64 * 256];  // h1 tile fp16, swz ^((row&15)<<4)

    const int tid = threadIdx.x;
    const int l = tid & 63;
    const int w = tid >> 6;
    const int fr = l & 15;
    const int fg = l >> 4;
    const int t0 = blockIdx.x;
    const int niter = (ntiles - t0 + NBLK - 1) / NBLK;   // wave-uniform

    // ---- prologue: stage tile t0 into xs[0], prefetch tile t0+NBLK
    {
        const float4* xg = (const float4*)(x + (size_t)t0 * 4096);
#pragma unroll
        for (int i = 0; i < 2; ++i) {
            int f4 = tid + i * 512;
            float4 v = xg[f4];
            int srow = f4 >> 4, c4 = f4 & 15;
            f16x4 b;
            b[0] = (_Float16)v.x; b[1] = (_Float16)v.y;
            b[2] = (_Float16)v.z; b[3] = (_Float16)v.w;
            int sbyte = (srow * 128 + c4 * 8) ^ ((srow & 7) << 4);
            *(f16x4*)((char*)xs[0] + sbyte) = b;
        }
    }
    float4 pf0, pf1;
    {
        int tn = t0 + NBLK;
        if (tn >= ntiles) tn = 0;
        const float4* xg = (const float4*)(x + (size_t)tn * 4096);
        pf0 = xg[tid];
        pf1 = xg[tid + 512];
    }
    __syncthreads();

    if (w < 4) {
        // ================= G1 producer: GEMM1 for tile it ====================
        f16x8 w1r[4][2];   // [ct][ks], ctg = 4w+ct  (32 regs)
#pragma unroll
        for (int ct = 0; ct < 4; ++ct)
#pragma unroll
            for (int ks = 0; ks < 2; ++ks) {
                int ctg = (w << 2) + ct;
                w1r[ct][ks] = *(const f16x8*)(w1g + (((ctg << 1) + ks) << 9) + (l << 3));
            }
#pragma unroll
        for (int ct = 0; ct < 4; ++ct)
#pragma unroll
            for (int ks = 0; ks < 2; ++ks) pin_reg(w1r[ct][ks]);
        f32x4 b1v[4];
#pragma unroll
        for (int ct = 0; ct < 4; ++ct)
            b1v[ct] = *(const f32x4*)(pb1 + (w << 6) + (ct << 4) + (fg << 2));

        int buf = 0, hb = 0;
        for (int it = 0; it <= niter; ++it) {
            if (it < niter) {
#pragma unroll
                for (int rt = 0; rt < 4; ++rt) {
                    f32x4 acc[4] = {};
#pragma unroll
                    for (int ks = 0; ks < 2; ++ks) {
                        int row = (rt << 4) + fr;
                        int byte = ((row << 7) + (ks << 6) + (fg << 4)) ^ ((row & 7) << 4);
                        f16x8 bd = *(const f16x8*)((char*)xs[buf] + byte);
#pragma unroll
                        for (int ct = 0; ct < 4; ++ct)
                            acc[ct] = __builtin_amdgcn_mfma_f32_16x16x32_f16(w1r[ct][ks], bd, acc[ct], 0, 0, 0);
                    }
#pragma unroll
                    for (int ct = 0; ct < 4; ++ct) {
                        int c0 = (w << 6) + (ct << 4) + (fg << 2);
                        int rown = (rt << 4) + fr;
                        f16x4 o;
                        o[0] = (_Float16)fmaxf(acc[ct][0] + b1v[ct][0], 0.f);
                        o[1] = (_Float16)fmaxf(acc[ct][1] + b1v[ct][1], 0.f);
                        o[2] = (_Float16)fmaxf(acc[ct][2] + b1v[ct][2], 0.f);
                        o[3] = (_Float16)fmaxf(acc[ct][3] + b1v[ct][3], 0.f);
                        int byte = ((rown << 9) + (c0 << 1)) ^ ((rown & 15) << 4);
                        *(f16x4*)((char*)h1s[hb] + byte) = o;
                    }
                }
            }
            STAGE_AND_PREFETCH(buf ^ 1, it)
            __syncthreads();
            buf ^= 1; hb ^= 1;
        }
    } else {
        // ================= G2 consumer: GEMM2+pool for tile it-1 =============
        const int wg = w - 4;
        f16x8 w2r[4][8];   // [ct][ks], ctg = 4wg+ct  (128 regs)
#pragma unroll
        for (int ct = 0; ct < 4; ++ct)
#pragma unroll
            for (int ks = 0; ks < 8; ++ks) {
                int ctg = (wg << 2) + ct;
                w2r[ct][ks] = *(const f16x8*)(w2g + (((ctg << 3) + ks) << 9) + (l << 3));
            }
#pragma unroll
        for (int ct = 0; ct < 4; ++ct)
#pragma unroll
            for (int ks = 0; ks < 8; ++ks) pin_reg(w2r[ct][ks]);
        f32x4 b2v[4];
#pragma unroll
        for (int ct = 0; ct < 4; ++ct)
            b2v[ct] = *(const f32x4*)(pb2 + (wg << 6) + (ct << 4) + (fg << 2));

        float psum[4][4] = {};
        int buf = 0, hb = 0;
        for (int it = 0; it <= niter; ++it) {
            if (it >= 1) {
#pragma unroll
                for (int rt = 0; rt < 4; ++rt) {
                    f32x4 acc2[4] = {};
#pragma unroll
                    for (int ks = 0; ks < 8; ++ks) {
                        int row = (rt << 4) + fr;
                        int byte = ((row << 9) + (ks << 6) + (fg << 4)) ^ ((row & 15) << 4);
                        f16x8 bd = *(const f16x8*)((char*)h1s[hb ^ 1] + byte);
#pragma unroll
                        for (int ct = 0; ct < 4; ++ct)
                            acc2[ct] = __builtin_amdgcn_mfma_f32_16x16x32_f16(w2r[ct][ks], bd, acc2[ct], 0, 0, 0);
                    }
#pragma unroll
                    for (int ct = 0; ct < 4; ++ct)
#pragma unroll
                        for (int r = 0; r < 4; ++r)
                            psum[ct][r] += fmaxf(acc2[ct][r] + b2v[ct][r], 0.f);
                }
            }
            STAGE_AND_PREFETCH(buf ^ 1, it)
            __syncthreads();
            buf ^= 1; hb ^= 1;
        }
        // ---- reduce psum over the 16 fr-lanes, one atomicAdd per col
#pragma unroll
        for (int ct = 0; ct < 4; ++ct)
#pragma unroll
            for (int r = 0; r < 4; ++r) {
                float v = psum[ct][r];
                v += __shfl_xor(v, 1, 64);
                v += __shfl_xor(v, 2, 64);
                v += __shfl_xor(v, 4, 64);
                v += __shfl_xor(v, 8, 64);
                if (fr == 0) atomicAdd(&gsum[(wg << 6) + (ct << 4) + (fg << 2) + r], v);
            }
    }
}

// ---------------- tail: split-K parallel rho + head (fp32, 1024 threads) ----
__global__ __launch_bounds__(1024) void tail_kernel(
    const float* __restrict__ gsum, const float* __restrict__ xst,
    const float* __restrict__ pw3, const float* __restrict__ pb3,
    const float* __restrict__ rw1, const float* __restrict__ rb1,
    const float* __restrict__ rw2, const float* __restrict__ rb2,
    const float* __restrict__ rw3, const float* __restrict__ rb3,
    const float* __restrict__ w1, const float* __restrict__ b1,
    const float* __restrict__ w2, const float* __restrict__ b2,
    const float* __restrict__ w3, const float* __restrict__ b3,
    float* __restrict__ out, float nf) {
    __shared__ float fp[128], r1[256], r2[256], tc[144], t1[256], t2[256];
    __shared__ float part[8][256];
    const int t = threadIdx.x;

    {   // fp = nf*pb3 + gsum @ pw3  (256->128, 8-way)
        int j = t & 127, q = t >> 7;
        float s = 0.f;
        for (int i = 32 * q; i < 32 * q + 32; ++i) s += gsum[i] * pw3[i * 128 + j];
        part[q][j] = s;
    }
    __syncthreads();
    if (t < 128) { float s = nf * pb3[t]; for (int q = 0; q < 8; ++q) s += part[q][t]; fp[t] = s; }
    __syncthreads();
    {   // r1 = relu(fp @ rw1 + rb1)  (128->256, 4-way)
        int j = t & 255, q = t >> 8;
        float s = 0.f;
        for (int i = 32 * q; i < 32 * q + 32; ++i) s += fp[i] * rw1[i * 256 + j];
        part[q][j] = s;
    }
    __syncthreads();
    if (t < 256) { float s = rb1[t]; for (int q = 0; q < 4; ++q) s += part[q][t]; r1[t] = fmaxf(s, 0.f); }
    __syncthreads();
    {   // r2 = relu(r1 @ rw2 + rb2)  (256->256, 4-way)
        int j = t & 255, q = t >> 8;
        float s = 0.f;
        for (int i = 64 * q; i < 64 * q + 64; ++i) s += r1[i] * rw2[i * 256 + j];
        part[q][j] = s;
    }
    __syncthreads();
    if (t < 256) { float s = rb2[t]; for (int q = 0; q < 4; ++q) s += part[q][t]; r2[t] = fmaxf(s, 0.f); }
    __syncthreads();
    {   // tc[0:128] = r2 @ rw3 + rb3  (256->128, 8-way)
        int j = t & 127, q = t >> 7;
        float s = 0.f;
        for (int i = 32 * q; i < 32 * q + 32; ++i) s += r2[i] * rw3[i * 128 + j];
        part[q][j] = s;
    }
    __syncthreads();
    if (t < 128) { float s = rb3[t]; for (int q = 0; q < 8; ++q) s += part[q][t]; tc[t] = s; }
    else if (t < 144) tc[t] = xst[t - 128];
    __syncthreads();
    {   // t1 = relu(tc @ w1 + b1)  (144->256, 4-way, 36 each)
        int j = t & 255, q = t >> 8;
        float s = 0.f;
        for (int i = 36 * q; i < 36 * q + 36; ++i) s += tc[i] * w1[i * 256 + j];
        part[q][j] = s;
    }
    __syncthreads();
    if (t < 256) { float s = b1[t]; for (int q = 0; q < 4; ++q) s += part[q][t]; t1[t] = fmaxf(s, 0.f); }
    __syncthreads();
    {   // t2 = relu(t1 @ w2 + b2)  (256->256, 4-way)
        int j = t & 255, q = t >> 8;
        float s = 0.f;
        for (int i = 64 * q; i < 64 * q + 64; ++i) s += t1[i] * w2[i * 256 + j];
        part[q][j] = s;
    }
    __syncthreads();
    if (t < 256) { float s = b2[t]; for (int q = 0; q < 4; ++q) s += part[q][t]; t2[t] = fmaxf(s, 0.f); }
    __syncthreads();
    {   // out = t2 @ w3 + b3  (256->5, 4-way)
        int j = t & 255, q = t >> 8;
        if (j < 5) {
            float s = 0.f;
            for (int i = 64 * q; i < 64 * q + 64; ++i) s += t2[i] * w3[i * 5 + j];
            part[q][j] = s;
        }
    }
    __syncthreads();
    if (t < 5) { float s = b3[t]; for (int q = 0; q < 4; ++q) s += part[q][t]; out[t] = s; }
}

extern "C" void kernel_launch(void* const* d_in, const int* in_sizes, int n_in,
                              void* d_out, int out_size, void* d_ws, size_t ws_size,
                              hipStream_t stream) {
    (void)n_in; (void)out_size; (void)ws_size;
    const float* x   = (const float*)d_in[0];
    const float* xst = (const float*)d_in[1];
    const float* pw1 = (const float*)d_in[2];
    const float* pb1 = (const float*)d_in[3];
    const float* pw2 = (const float*)d_in[4];
    const float* pb2 = (const float*)d_in[5];
    const float* pw3 = (const float*)d_in[6];
    const float* pb3 = (const float*)d_in[7];
    const float* rw1 = (const float*)d_in[8];
    const float* rb1 = (const float*)d_in[9];
    const float* rw2 = (const float*)d_in[10];
    const float* rb2 = (const float*)d_in[11];
    const float* rw3 = (const float*)d_in[12];
    const float* rb3 = (const float*)d_in[13];
    const float* w1  = (const float*)d_in[14];
    const float* b1  = (const float*)d_in[15];
    const float* w2  = (const float*)d_in[16];
    const float* b2  = (const float*)d_in[17];
    const float* w3  = (const float*)d_in[18];
    const float* b3  = (const float*)d_in[19];
    float* out = (float*)d_out;

    int n = in_sizes[0] / 64;      // 400000
    int ntiles = n >> 6;           // 6250

    char* ws = (char*)d_ws;
    float* gsum = (float*)ws;                       // 256 f32 (1KB)
    _Float16* w1f = (_Float16*)(ws + 1024);         // 16384 f16 (32KB)
    _Float16* w2f = (_Float16*)(ws + 1024 + 32768); // 65536 f16 (128KB)

    prep_kernel<<<160, 512, 0, stream>>>(pw1, pw2, w1f, w2f, gsum,
                                         pw3, rw1, rw2, rw3, w1, w2, w3);
    phi_kernel<<<NBLK, 512, 0, stream>>>(x, pb1, pb2, w1f, w2f, gsum, ntiles);
    tail_kernel<<<1, 1024, 0, stream>>>(gsum, xst, pw3, pb3, rw1, rb1, rw2, rb2,
                                        rw3, rb3, w1, b1, w2, b2, w3, b3, out, (float)n);
}

// Round 12
// 124.704 us; speedup vs baseline: 2.3471x; 1.0658x over previous
//
#include <hip/hip_runtime.h>

// DeepSets fused kernel for MI355X (gfx950) — round 12.
// Base = r5's champion symmetric phi (85.8us, 116 VGPR, no spill).
// Changes: (1) loop reordered so global x prefetch is ISSUED before GEMM1
// (stage -> issue loads -> GEMM1 -> barrier -> GEMM2): the compiler's
// vmcnt(0)-before-barrier drain no longer exposes ~900cy HBM latency per iter;
// (2) v_cvt_pkrtz packed f32->f16 in staging + GEMM1 epilogue (halves cvt VALU).
// Keep r6 split-K tail + L3 warm.

typedef unsigned short u16;
typedef _Float16 f16x8 __attribute__((ext_vector_type(8)));
typedef _Float16 f16x2 __attribute__((ext_vector_type(2)));
typedef float f32x4 __attribute__((ext_vector_type(4)));
typedef int i32x4 __attribute__((ext_vector_type(4)));

#define NBLK 256

// ---------------- prep: fp32 weights -> fp16 fragments, zero gsum, warm L3 ---
// Fragment layout (validated r1-r11): lane l, elem j holds W[k=32*ks+8*(l>>4)+j][16*ctg+(l&15)]
// at frag[((ctg*KS+ks)*64 + l)*8 + j]. Used as MFMA *A* operand: D = W^T X^T = (XW)^T.
__global__ void prep_kernel(const float* __restrict__ pw1, const float* __restrict__ pw2,
                            _Float16* __restrict__ w1f, _Float16* __restrict__ w2f,
                            float* __restrict__ gsum,
                            const float* __restrict__ pw3, const float* __restrict__ rw1,
                            const float* __restrict__ rw2, const float* __restrict__ rw3,
                            const float* __restrict__ hw1, const float* __restrict__ hw2,
                            const float* __restrict__ hw3) {
    int idx = blockIdx.x * blockDim.x + threadIdx.x;   // 160*512 = 81920
    if (idx < 256) gsum[idx] = 0.f;
    if (idx < 16384) {  // pw1: 64x256, KS=2
        int j = idx & 7, l = (idx >> 3) & 63, ks = (idx >> 9) & 1, ct = idx >> 10;
        int k = 32 * ks + 8 * (l >> 4) + j;
        int col = 16 * ct + (l & 15);
        w1f[idx] = (_Float16)pw1[k * 256 + col];
    } else {            // pw2: 256x256, KS=8
        int o = idx - 16384;
        int j = o & 7, l = (o >> 3) & 63, ks = (o >> 9) & 7, ct = o >> 12;
        int k = 32 * ks + 8 * (l >> 4) + j;
        int col = 16 * ct + (l & 15);
        w2f[o] = (_Float16)pw2[k * 256 + col];
    }
    // warm rho/head weights into L3 so tail_kernel doesn't stream cold HBM
    float s = 0.f;
    if (idx < 32768) s += pw3[idx];
    if (idx < 32768) s += rw1[idx];
    if (idx < 65536) s += rw2[idx];
    if (idx < 32768) s += rw3[idx];
    if (idx < 36864) s += hw1[idx];
    if (idx < 65536) s += hw2[idx];
    if (idx < 1280)  s += hw3[idx];
    asm volatile("" :: "v"(s));
}

__device__ __forceinline__ void pin_reg(f16x8& v) {
    i32x4 t = __builtin_bit_cast(i32x4, v);
    asm volatile("" : "+v"(t));
    v = __builtin_bit_cast(f16x8, t);
}
__device__ __forceinline__ unsigned pk(float a, float b) {
    return __builtin_bit_cast(unsigned, __builtin_amdgcn_cvt_pkrtz(a, b));
}

// ---------------- fused phi + pool (persistent) ------------------------------
// 8 waves; wave w owns cols [32w, 32w+32); dbuf xs + dbuf h1s, ONE barrier/iter.
__global__ __attribute__((amdgpu_flat_work_group_size(512, 512), amdgpu_waves_per_eu(2, 2)))
void phi_kernel(
    const float* __restrict__ x,
    const float* __restrict__ pb1, const float* __restrict__ pb2,
    const _Float16* __restrict__ w1g, const _Float16* __restrict__ w2g,
    float* __restrict__ gsum, int ntiles) {
    __shared__ __align__(16) u16 xs[2][64 * 64];    // x tile fp16, swz ^((row&7)<<4)
    __shared__ __align__(16) u16 h1s[2][64 * 256];  // h1 tile fp16, swz ^((row&15)<<4)

    const int tid = threadIdx.x;
    const int l = tid & 63;
    const int w = tid >> 6;
    const int fr = l & 15;
    const int fg = l >> 4;
    const int wb = w * 32;

    // ---- preload weight fragments into registers (loop-invariant, pinned)
    f16x8 w1r[2][2];   // [ct][ks]
#pragma unroll
    for (int ct = 0; ct < 2; ++ct)
#pragma unroll
        for (int ks = 0; ks < 2; ++ks) {
            int ctg = 2 * w + ct;
            w1r[ct][ks] = *(const f16x8*)(w1g + (((ctg << 1) + ks) << 9) + (l << 3));
        }
    f16x8 w2r[2][8];   // [ct][ks]
#pragma unroll
    for (int ct = 0; ct < 2; ++ct)
#pragma unroll
        for (int ks = 0; ks < 8; ++ks) {
            int ctg = 2 * w + ct;
            w2r[ct][ks] = *(const f16x8*)(w2g + (((ctg << 3) + ks) << 9) + (l << 3));
        }
#pragma unroll
    for (int ct = 0; ct < 2; ++ct) {
#pragma unroll
        for (int ks = 0; ks < 2; ++ks) pin_reg(w1r[ct][ks]);
#pragma unroll
        for (int ks = 0; ks < 8; ++ks) pin_reg(w2r[ct][ks]);
    }
    f32x4 b1v[2], b2v[2];
#pragma unroll
    for (int ct = 0; ct < 2; ++ct) {
        int c0 = wb + ct * 16 + fg * 4;
        b1v[ct] = *(const f32x4*)(pb1 + c0);
        b2v[ct] = *(const f32x4*)(pb2 + c0);
    }

    float psum[2][4] = {{0.f, 0.f, 0.f, 0.f}, {0.f, 0.f, 0.f, 0.f}};

    const int t0 = blockIdx.x;
    // ---- prologue: stage tile t0 into xs[0], prefetch t0+NBLK into regs
    {
        const float4* xg = (const float4*)(x + (size_t)t0 * 4096);
#pragma unroll
        for (int i = 0; i < 2; ++i) {
            int f4 = tid + i * 512;
            float4 v = xg[f4];
            int row = f4 >> 4, c4 = f4 & 15;
            uint2 o;
            o.x = pk(v.x, v.y);
            o.y = pk(v.z, v.w);
            int byte = (row * 128 + c4 * 8) ^ ((row & 7) << 4);
            *(uint2*)((char*)xs[0] + byte) = o;
        }
    }
    float4 pf0, pf1;
    {
        int tn = (t0 + NBLK < ntiles) ? t0 + NBLK : 0;
        const float4* xg = (const float4*)(x + (size_t)tn * 4096);
        pf0 = xg[tid];
        pf1 = xg[tid + 512];
    }
    __syncthreads();

    int buf = 0, hb = 0;
    for (int t = t0; t < ntiles; t += NBLK) {
        // ---- stage next x tile FIRST (consume pf regs -> xs[buf^1])
#pragma unroll
        for (int i = 0; i < 2; ++i) {
            float4 v = i ? pf1 : pf0;
            int f4 = tid + i * 512;
            int row = f4 >> 4, c4 = f4 & 15;
            uint2 o;
            o.x = pk(v.x, v.y);
            o.y = pk(v.z, v.w);
            int byte = (row * 128 + c4 * 8) ^ ((row & 7) << 4);
            *(uint2*)((char*)xs[buf ^ 1] + byte) = o;
        }
        // ---- ISSUE global loads for t+2*NBLK now: they have all of GEMM1 to land
        {
            int tn = (t + 2 * NBLK < ntiles) ? t + 2 * NBLK : 0;
            const float4* xg = (const float4*)(x + (size_t)tn * 4096);
            pf0 = xg[tid];
            pf1 = xg[tid + 512];
        }

        // ---- GEMM1: D1 = (x@pw1)^T from xs[buf] -> h1s[hb]
        {
            f32x4 acc[2][4] = {};
#pragma unroll
            for (int ks = 0; ks < 2; ++ks) {
                f16x8 bd[4];
#pragma unroll
                for (int rt = 0; rt < 4; ++rt) {
                    int row = (rt << 4) + fr;
                    int byte = ((row << 7) + (ks << 6) + (fg << 4)) ^ ((row & 7) << 4);
                    bd[rt] = *(const f16x8*)((char*)xs[buf] + byte);
                }
#pragma unroll
                for (int ct = 0; ct < 2; ++ct)
#pragma unroll
                    for (int rt = 0; rt < 4; ++rt)
                        acc[ct][rt] = __builtin_amdgcn_mfma_f32_16x16x32_f16(w1r[ct][ks], bd[rt], acc[ct][rt], 0, 0, 0);
            }
            // epilogue: bias+relu, packed cvt; lane holds h-cols c0..c0+3 of row rown
#pragma unroll
            for (int ct = 0; ct < 2; ++ct) {
                int c0 = wb + ct * 16 + fg * 4;
#pragma unroll
                for (int rt = 0; rt < 4; ++rt) {
                    int rown = (rt << 4) + fr;
                    uint2 o;
                    o.x = pk(fmaxf(acc[ct][rt][0] + b1v[ct][0], 0.f),
                             fmaxf(acc[ct][rt][1] + b1v[ct][1], 0.f));
                    o.y = pk(fmaxf(acc[ct][rt][2] + b1v[ct][2], 0.f),
                             fmaxf(acc[ct][rt][3] + b1v[ct][3], 0.f));
                    int byte = ((rown << 9) + (c0 << 1)) ^ ((rown & 15) << 4);
                    *(uint2*)((char*)h1s[hb] + byte) = o;
                }
            }
        }
        __syncthreads();   // h1s[hb] + xs[buf^1] visible; prefetch loads landed

        // ---- GEMM2: D2 = (h1@pw2)^T, pool into psum
        {
            f32x4 acc2[2][4] = {};
#pragma unroll
            for (int ks = 0; ks < 8; ++ks) {
                f16x8 bd[4];
#pragma unroll
                for (int rt = 0; rt < 4; ++rt) {
                    int row = (rt << 4) + fr;
                    int byte = ((row << 9) + (ks << 6) + (fg << 4)) ^ ((row & 15) << 4);
                    bd[rt] = *(const f16x8*)((char*)h1s[hb] + byte);
                }
#pragma unroll
                for (int ct = 0; ct < 2; ++ct)
#pragma unroll
                    for (int rt = 0; rt < 4; ++rt)
                        acc2[ct][rt] = __builtin_amdgcn_mfma_f32_16x16x32_f16(w2r[ct][ks], bd[rt], acc2[ct][rt], 0, 0, 0);
            }
#pragma unroll
            for (int ct = 0; ct < 2; ++ct)
#pragma unroll
                for (int r = 0; r < 4; ++r) {
                    float v = 0.f;
#pragma unroll
                    for (int rt = 0; rt < 4; ++rt)
                        v += fmaxf(acc2[ct][rt][r] + b2v[ct][r], 0.f);
                    psum[ct][r] += v;
                }
        }
        buf ^= 1;
        hb ^= 1;
    }

    // ---- final: reduce psum over the 16 fr-lanes, one atomicAdd per col
#pragma unroll
    for (int ct = 0; ct < 2; ++ct)
#pragma unroll
        for (int r = 0; r < 4; ++r) {
            float v = psum[ct][r];
            v += __shfl_xor(v, 1, 64);
            v += __shfl_xor(v, 2, 64);
            v += __shfl_xor(v, 4, 64);
            v += __shfl_xor(v, 8, 64);
            if (fr == 0) atomicAdd(&gsum[wb + ct * 16 + fg * 4 + r], v);
        }
}

// ---------------- tail: split-K parallel rho + head (fp32, 1024 threads) ----
__global__ __launch_bounds__(1024) void tail_kernel(
    const float* __restrict__ gsum, const float* __restrict__ xst,
    const float* __restrict__ pw3, const float* __restrict__ pb3,
    const float* __restrict__ rw1, const float* __restrict__ rb1,
    const float* __restrict__ rw2, const float* __restrict__ rb2,
    const float* __restrict__ rw3, const float* __restrict__ rb3,
    const float* __restrict__ w1, const float* __restrict__ b1,
    const float* __restrict__ w2, const float* __restrict__ b2,
    const float* __restrict__ w3, const float* __restrict__ b3,
    float* __restrict__ out, float nf) {
    __shared__ float fp[128], r1[256], r2[256], tc[144], t1[256], t2[256];
    __shared__ float part[8][256];
    const int t = threadIdx.x;

    {   // fp = nf*pb3 + gsum @ pw3  (256->128, 8-way)
        int j = t & 127, q = t >> 7;
        float s = 0.f;
        for (int i = 32 * q; i < 32 * q + 32; ++i) s += gsum[i] * pw3[i * 128 + j];
        part[q][j] = s;
    }
    __syncthreads();
    if (t < 128) { float s = nf * pb3[t]; for (int q = 0; q < 8; ++q) s += part[q][t]; fp[t] = s; }
    __syncthreads();
    {   // r1 = relu(fp @ rw1 + rb1)  (128->256, 4-way)
        int j = t & 255, q = t >> 8;
        float s = 0.f;
        for (int i = 32 * q; i < 32 * q + 32; ++i) s += fp[i] * rw1[i * 256 + j];
        part[q][j] = s;
    }
    __syncthreads();
    if (t < 256) { float s = rb1[t]; for (int q = 0; q < 4; ++q) s += part[q][t]; r1[t] = fmaxf(s, 0.f); }
    __syncthreads();
    {   // r2 = relu(r1 @ rw2 + rb2)  (256->256, 4-way)
        int j = t & 255, q = t >> 8;
        float s = 0.f;
        for (int i = 64 * q; i < 64 * q + 64; ++i) s += r1[i] * rw2[i * 256 + j];
        part[q][j] = s;
    }
    __syncthreads();
    if (t < 256) { float s = rb2[t]; for (int q = 0; q < 4; ++q) s += part[q][t]; r2[t] = fmaxf(s, 0.f); }
    __syncthreads();
    {   // tc[0:128] = r2 @ rw3 + rb3  (256->128, 8-way)
        int j = t & 127, q = t >> 7;
        float s = 0.f;
        for (int i = 32 * q; i < 32 * q + 32; ++i) s += r2[i] * rw3[i * 128 + j];
        part[q][j] = s;
    }
    __syncthreads();
    if (t < 128) { float s = rb3[t]; for (int q = 0; q < 8; ++q) s += part[q][t]; tc[t] = s; }
    else if (t < 144) tc[t] = xst[t - 128];
    __syncthreads();
    {   // t1 = relu(tc @ w1 + b1)  (144->256, 4-way, 36 each)
        int j = t & 255, q = t >> 8;
        float s = 0.f;
        for (int i = 36 * q; i < 36 * q + 36; ++i) s += tc[i] * w1[i * 256 + j];
        part[q][j] = s;
    }
    __syncthreads();
    if (t < 256) { float s = b1[t]; for (int q = 0; q < 4; ++q) s += part[q][t]; t1[t] = fmaxf(s, 0.f); }
    __syncthreads();
    {   // t2 = relu(t1 @ w2 + b2)  (256->256, 4-way)
        int j = t & 255, q = t >> 8;
        float s = 0.f;
        for (int i = 64 * q; i < 64 * q + 64; ++i) s += t1[i] * w2[i * 256 + j];
        part[q][j] = s;
    }
    __syncthreads();
    if (t < 256) { float s = b2[t]; for (int q = 0; q < 4; ++q) s += part[q][t]; t2[t] = fmaxf(s, 0.f); }
    __syncthreads();
    {   // out = t2 @ w3 + b3  (256->5, 4-way)
        int j = t & 255, q = t >> 8;
        if (j < 5) {
            float s = 0.f;
            for (int i = 64 * q; i < 64 * q + 64; ++i) s += t2[i] * w3[i * 5 + j];
            part[q][j] = s;
        }
    }
    __syncthreads();
    if (t < 5) { float s = b3[t]; for (int q = 0; q < 4; ++q) s += part[q][t]; out[t] = s; }
}

extern "C" void kernel_launch(void* const* d_in, const int* in_sizes, int n_in,
                              void* d_out, int out_size, void* d_ws, size_t ws_size,
                              hipStream_t stream) {
    (void)n_in; (void)out_size; (void)ws_size;
    const float* x   = (const float*)d_in[0];
    const float* xst = (const float*)d_in[1];
    const float* pw1 = (const float*)d_in[2];
    const float* pb1 = (const float*)d_in[3];
    const float* pw2 = (const float*)d_in[4];
    const float* pb2 = (const float*)d_in[5];
    const float* pw3 = (const float*)d_in[6];
    const float* pb3 = (const float*)d_in[7];
    const float* rw1 = (const float*)d_in[8];
    const float* rb1 = (const float*)d_in[9];
    const float* rw2 = (const float*)d_in[10];
    const float* rb2 = (const float*)d_in[11];
    const float* rw3 = (const float*)d_in[12];
    const float* rb3 = (const float*)d_in[13];
    const float* w1  = (const float*)d_in[14];
    const float* b1  = (const float*)d_in[15];
    const float* w2  = (const float*)d_in[16];
    const float* b2  = (const float*)d_in[17];
    const float* w3  = (const float*)d_in[18];
    const float* b3  = (const float*)d_in[19];
    float* out = (float*)d_out;

    int n = in_sizes[0] / 64;      // 400000
    int ntiles = n >> 6;           // 6250

    char* ws = (char*)d_ws;
    float* gsum = (float*)ws;                       // 256 f32 (1KB)
    _Float16* w1f = (_Float16*)(ws + 1024);         // 16384 f16 (32KB)
    _Float16* w2f = (_Float16*)(ws + 1024 + 32768); // 65536 f16 (128KB)

    prep_kernel<<<160, 512, 0, stream>>>(pw1, pw2, w1f, w2f, gsum,
                                         pw3, rw1, rw2, rw3, w1, w2, w3);
    phi_kernel<<<NBLK, 512, 0, stream>>>(x, pb1, pb2, w1f, w2f, gsum, ntiles);
    tail_kernel<<<1, 1024, 0, stream>>>(gsum, xst, pw3, pb3, rw1, rb1, rw2, rb2,
                                        rw3, rb3, w1, b1, w2, b2, w3, b3, out, (float)n);
}